// Round 2
// baseline (1134.669 us; speedup 1.0000x reference)
//
#include <hip/hip_runtime.h>
#include <hip/hip_bf16.h>

#define HW   4096
#define CH   128
#define NCTX 8

using bf16 = __hip_bfloat16;
typedef float f32x4 __attribute__((ext_vector_type(4)));
typedef short s16x8 __attribute__((ext_vector_type(8)));

// ---------------- normalize feat_tar [4096,128] f32 -> bf16 [4096,128] -------
__global__ __launch_bounds__(64) void norm_tar(const float* __restrict__ ft,
                                               bf16* __restrict__ ftn) {
    int t = blockIdx.x;
    int lane = threadIdx.x;
    float2 v = ((const float2*)(ft + (size_t)t * CH))[lane];
    float s = v.x * v.x + v.y * v.y;
    #pragma unroll
    for (int off = 1; off < 64; off <<= 1) s += __shfl_xor(s, off, 64);
    float scale = 1.0f / fmaxf(sqrtf(s), 1e-12f);
    __hip_bfloat162 h;
    h.x = __float2bfloat16(v.x * scale);
    h.y = __float2bfloat16(v.y * scale);
    ((__hip_bfloat162*)(ftn + (size_t)t * CH))[lane] = h;
}

// ------- normalize + transpose feat_refs [8,128,4096] f32 -> bf16 [8,4096,128]
__global__ __launch_bounds__(256) void norm_refs(const float* __restrict__ fr,
                                                 bf16* __restrict__ frt) {
    int idx = blockIdx.x * 256 + threadIdx.x;   // 0..32767 = n*4096 + r
    int n = idx >> 12;
    int r = idx & 4095;
    const float* src = fr + (size_t)n * CH * HW + r;
    float s = 0.f;
    #pragma unroll
    for (int c = 0; c < CH; ++c) {
        float v = src[(size_t)c * HW];
        s += v * v;
    }
    float scale = 1.0f / fmaxf(sqrtf(s), 1e-12f);
    bf16* dst = frt + (size_t)idx * CH;
    #pragma unroll
    for (int c0 = 0; c0 < CH; c0 += 8) {
        union { bf16 h[8]; int4 v; } u;
        #pragma unroll
        for (int j = 0; j < 8; ++j)
            u.h[j] = __float2bfloat16(src[(size_t)(c0 + j) * HW] * scale);
        ((int4*)dst)[c0 / 8] = u.v;
    }
}

// ---------------- single-pass fused affinity GEMM + softmax ------------------
// Block = 16 t-rows x full r=4096 for one context n.  8 waves, 512 threads.
// Wave w owns r-columns w*16..w*16+15 of each 128-wide r-tile.
// acc[32] f32x4 = the entire softmax row set in registers (128 VGPR/lane):
// GEMM runs ONCE, softmax denominator comes from registers, no atomics,
// no second pass, no S buffer.
// n = bid & 7 -> all blocks of context n land on one XCD; B_n (1 MB) stays
// resident in that XCD's 4 MB L2 (bijective mapping, 2048 % 8 == 0).
// B staging: proven baseline pattern — int4 global->reg->XOR-swizzled LDS,
// double-buffered 256-column chunks (2 x 64 KB LDS).
__global__ __launch_bounds__(512) void affinity_fused(
    const bf16* __restrict__ A,   // [4096][128]   (t, c) normalized
    const bf16* __restrict__ Bt,  // [8][4096][128] (n, r, c) normalized
    float* __restrict__ out) {    // [8][4096][4096]
    __shared__ bf16 Bs[2][2][128 * 128];  // [buf][tile] 2 x 2 x 32 KB = 128 KB
    __shared__ float Ssum[8][16];         // cross-wave row-sum exchange

    int bid = blockIdx.x;               // 0..2047
    int n   = bid & 7;                  // XCD-pinned context
    int t0  = (bid >> 3) * 16;

    int tid  = threadIdx.x;
    int wave = tid >> 6, lane = tid & 63;
    int l15  = lane & 15, quad = lane >> 4;

    // A fragments direct from global (16x128 A-tile, shared by all 8 waves):
    // lane l15 -> t-row, quad -> k-octet within each K=32 block.
    s16x8 af[4];
    const s16x8* arow = (const s16x8*)(A + (size_t)(t0 + l15) * CH);
    #pragma unroll
    for (int kf = 0; kf < 4; ++kf) af[kf] = arow[kf * 4 + quad];

    const bf16* bsrc = Bt + (size_t)n * HW * CH;

    f32x4 acc[32] = {};                 // 32 r-tiles x 4 rows, static-indexed
    int4 stg[8];                        // staging regs: 256-col chunk / thread

    // Per-thread staging coords: q = tid + i*512 (16B chunk id, 0..4095),
    // tile = q>>11, row = (q&2047)>>4, c = (q&2047)&15.
    // LDS slot (row, c^(row&15)) holds global (row, c) — same swizzle as the
    // verified baseline; fragment reads XOR with l15.
    auto GLOAD = [&](int rc) {
        #pragma unroll
        for (int i = 0; i < 8; ++i) {
            int q = tid + i * 512;
            int tile = q >> 11, q2 = q & 2047;
            int row = q2 >> 4, c = q2 & 15;
            stg[i] = ((const int4*)(bsrc +
                      (size_t)(rc * 256 + tile * 128 + row) * CH))[c];
        }
    };
    auto SWRITE = [&](int buf) {
        #pragma unroll
        for (int i = 0; i < 8; ++i) {
            int q = tid + i * 512;
            int tile = q >> 11, q2 = q & 2047;
            int row = q2 >> 4, c = q2 & 15;
            ((int4*)Bs[buf][tile])[row * 16 + (c ^ (row & 15))] = stg[i];
        }
    };

    GLOAD(0);
    SWRITE(0);
    __syncthreads();

    int brow = wave * 16 + l15;
    #pragma unroll
    for (int rc = 0; rc < 16; ++rc) {
        int cur = rc & 1;
        if (rc < 15) GLOAD(rc + 1);     // issue next chunk; overlaps compute
        #pragma unroll
        for (int tile = 0; tile < 2; ++tile) {
            const s16x8* bb = (const s16x8*)Bs[cur][tile];
            s16x8 bfr[4];
            #pragma unroll
            for (int kf = 0; kf < 4; ++kf)
                bfr[kf] = bb[brow * 16 + ((kf * 4 + quad) ^ l15)];
            #pragma unroll
            for (int kf = 0; kf < 4; ++kf)
                acc[rc * 2 + tile] = __builtin_amdgcn_mfma_f32_16x16x32_bf16(
                    af[kf], bfr[kf], acc[rc * 2 + tile], 0, 0, 0);
        }
        if (rc < 15) {
            __syncthreads();            // all reads of Bs[cur^1] (prev) done
            SWRITE(cur ^ 1);            // waits vmcnt on stg as needed
            __syncthreads();            // writes visible before next compute
        }
    }

    // ---- epilogue: exp in-register, row sums, scale, stream out -------------
    // C/D layout (verified m89/m91): col = lane&15 (r), row = quad*4 + reg (t)
    float ps[4] = {0.f, 0.f, 0.f, 0.f};
    #pragma unroll
    for (int i = 0; i < 32; ++i) {
        #pragma unroll
        for (int rg = 0; rg < 4; ++rg) {
            float e = __expf(acc[i][rg]);   // logits in [-1,1]: exp safe
            acc[i][rg] = e;
            ps[rg] += e;
        }
    }
    #pragma unroll
    for (int off = 1; off < 16; off <<= 1) {  // reduce across the 16 r-cols
        #pragma unroll
        for (int rg = 0; rg < 4; ++rg) ps[rg] += __shfl_xor(ps[rg], off, 64);
    }
    if (l15 == 0) {
        #pragma unroll
        for (int rg = 0; rg < 4; ++rg) Ssum[wave][quad * 4 + rg] = ps[rg];
    }
    __syncthreads();
    float inv[4];
    #pragma unroll
    for (int rg = 0; rg < 4; ++rg) {
        float s = 0.f;
        #pragma unroll
        for (int w = 0; w < 8; ++w) s += Ssum[w][quad * 4 + rg];
        inv[rg] = 1.0f / s;             // s >= 4096/e: no eps needed
    }
    // Nontemporal stores: don't let the 537 MB stream evict B_n from L2.
    float* obase = out + ((size_t)n * HW + t0 + quad * 4) * HW + wave * 16 + l15;
    #pragma unroll
    for (int rg = 0; rg < 4; ++rg) {
        float iv = inv[rg];
        float* orow = obase + (size_t)rg * HW;
        #pragma unroll
        for (int i = 0; i < 32; ++i)
            __builtin_nontemporal_store(acc[i][rg] * iv, orow + i * 128);
    }
}

extern "C" void kernel_launch(void* const* d_in, const int* in_sizes, int n_in,
                              void* d_out, int out_size, void* d_ws, size_t ws_size,
                              hipStream_t stream) {
    const float* ft = (const float*)d_in[0];   // [4096,128]
    const float* fr = (const float*)d_in[1];   // [8,128,4096]
    float* out = (float*)d_out;                // [8,4096,4096]

    char* ws = (char*)d_ws;
    bf16* ftn = (bf16*)ws;                     // 1 MB
    bf16* frt = (bf16*)(ws + (1 << 20));       // 8 MB

    norm_tar<<<HW, 64, 0, stream>>>(ft, ftn);
    norm_refs<<<(NCTX * HW) / 256, 256, 0, stream>>>(fr, frt);
    affinity_fused<<<NCTX * (HW / 16), 512, 0, stream>>>(ftn, frt, out);
}

// Round 3
// 1127.496 us; speedup vs baseline: 1.0064x; 1.0064x over previous
//
#include <hip/hip_runtime.h>
#include <hip/hip_bf16.h>

#define HW   4096
#define CH   128
#define NCTX 8

using bf16 = __hip_bfloat16;
typedef float f32x4 __attribute__((ext_vector_type(4)));
typedef short s16x8 __attribute__((ext_vector_type(8)));

// ---------------- normalize feat_tar [4096,128] f32 -> bf16 [4096,128] -------
__global__ __launch_bounds__(64) void norm_tar(const float* __restrict__ ft,
                                               bf16* __restrict__ ftn) {
    int t = blockIdx.x;
    int lane = threadIdx.x;
    float2 v = ((const float2*)(ft + (size_t)t * CH))[lane];
    float s = v.x * v.x + v.y * v.y;
    #pragma unroll
    for (int off = 1; off < 64; off <<= 1) s += __shfl_xor(s, off, 64);
    float scale = 1.0f / fmaxf(sqrtf(s), 1e-12f);
    __hip_bfloat162 h;
    h.x = __float2bfloat16(v.x * scale);
    h.y = __float2bfloat16(v.y * scale);
    ((__hip_bfloat162*)(ftn + (size_t)t * CH))[lane] = h;
}

// ------- normalize + transpose feat_refs [8,128,4096] f32 -> bf16 [8,4096,128]
__global__ __launch_bounds__(256) void norm_refs(const float* __restrict__ fr,
                                                 bf16* __restrict__ frt) {
    int idx = blockIdx.x * 256 + threadIdx.x;   // 0..32767 = n*4096 + r
    int n = idx >> 12;
    int r = idx & 4095;
    const float* src = fr + (size_t)n * CH * HW + r;
    float s = 0.f;
    #pragma unroll
    for (int c = 0; c < CH; ++c) {
        float v = src[(size_t)c * HW];
        s += v * v;
    }
    float scale = 1.0f / fmaxf(sqrtf(s), 1e-12f);
    bf16* dst = frt + (size_t)idx * CH;
    #pragma unroll
    for (int c0 = 0; c0 < CH; c0 += 8) {
        union { bf16 h[8]; int4 v; } u;
        #pragma unroll
        for (int j = 0; j < 8; ++j)
            u.h[j] = __float2bfloat16(src[(size_t)(c0 + j) * HW] * scale);
        ((int4*)dst)[c0 / 8] = u.v;
    }
}

// ---------------- single-pass fused affinity GEMM + softmax ------------------
// Block = 16 t-rows x full r=4096 for one context n.  8 waves, 512 threads.
// acc[32] f32x4 = the whole softmax row set in registers: GEMM runs ONCE,
// denominator from registers, no atomics, no second pass.
// n = bid & 7 pins each context's B_n (1 MB) to one XCD's L2 (2048 % 8 == 0).
// Epilogue: scatter exp*inv into LDS (overlaying the dead B tiles), read back
// contiguously, NT-store full 128-B lines (fixes round-2's 4.2x write
// amplification: WRITE_SIZE 2.27 GB -> ~0.55 GB).
__global__ __launch_bounds__(512) void affinity_fused(
    const bf16* __restrict__ A,   // [4096][128]   (t, c) normalized
    const bf16* __restrict__ Bt,  // [8][4096][128] (n, r, c) normalized
    float* __restrict__ out) {    // [8][4096][4096]
    // Overlay: Bs [2][2][128*128] bf16 (131072 B) during GEMM;
    //          obuf [16][2052] f32 (131328 B) during epilogue (+4 pad: free
    //          2-way bank alias on scatter, contiguous read-back).
    __shared__ __align__(16) char smem[16 * 2052 * 4];
    __shared__ float Ssum[8][16];
    auto Bs   = reinterpret_cast<bf16 (*)[2][128 * 128]>(smem);  // [buf][tile]
    auto obuf = reinterpret_cast<float (*)[2052]>(smem);

    int bid = blockIdx.x;               // 0..2047
    int n   = bid & 7;                  // XCD-pinned context
    int t0  = (bid >> 3) * 16;

    int tid  = threadIdx.x;
    int wave = tid >> 6, lane = tid & 63;
    int l15  = lane & 15, quad = lane >> 4;

    // A fragments direct from global (16x128 A-tile, shared by all 8 waves):
    s16x8 af[4];
    const s16x8* arow = (const s16x8*)(A + (size_t)(t0 + l15) * CH);
    #pragma unroll
    for (int kf = 0; kf < 4; ++kf) af[kf] = arow[kf * 4 + quad];

    const bf16* bsrc = Bt + (size_t)n * HW * CH;

    f32x4 acc[32] = {};                 // 32 r-tiles x 4 rows, static-indexed
    int4 stg[8];                        // staging regs: 256-col chunk / thread

    // q = tid + i*512 (16B chunk id), tile = q>>11, row = (q&2047)>>4,
    // c = q&15.  LDS slot (row, c^(row&15)) holds global (row, c).
    auto GLOAD = [&](int rc) {
        #pragma unroll
        for (int i = 0; i < 8; ++i) {
            int q = tid + i * 512;
            int tile = q >> 11, q2 = q & 2047;
            int row = q2 >> 4, c = q2 & 15;
            stg[i] = ((const int4*)(bsrc +
                      (size_t)(rc * 256 + tile * 128 + row) * CH))[c];
        }
    };
    auto SWRITE = [&](int buf) {
        #pragma unroll
        for (int i = 0; i < 8; ++i) {
            int q = tid + i * 512;
            int tile = q >> 11, q2 = q & 2047;
            int row = q2 >> 4, c = q2 & 15;
            ((int4*)Bs[buf][tile])[row * 16 + (c ^ (row & 15))] = stg[i];
        }
    };

    GLOAD(0);
    SWRITE(0);
    __syncthreads();

    int brow = wave * 16 + l15;
    #pragma unroll
    for (int rc = 0; rc < 16; ++rc) {
        int cur = rc & 1;
        if (rc < 15) GLOAD(rc + 1);     // issue next chunk; overlaps compute
        #pragma unroll
        for (int tile = 0; tile < 2; ++tile) {
            const s16x8* bb = (const s16x8*)Bs[cur][tile];
            s16x8 bfr[4];
            #pragma unroll
            for (int kf = 0; kf < 4; ++kf)
                bfr[kf] = bb[brow * 16 + ((kf * 4 + quad) ^ l15)];
            #pragma unroll
            for (int kf = 0; kf < 4; ++kf)
                acc[rc * 2 + tile] = __builtin_amdgcn_mfma_f32_16x16x32_bf16(
                    af[kf], bfr[kf], acc[rc * 2 + tile], 0, 0, 0);
        }
        if (rc < 15) {
            __syncthreads();            // all reads of Bs[cur^1] (prev) done
            SWRITE(cur ^ 1);
            __syncthreads();            // writes visible before next compute
        }
    }

    // ---- epilogue -----------------------------------------------------------
    // C/D layout (verified m89/m91): col = lane&15 (r), row = quad*4 + reg (t)
    float ps[4] = {0.f, 0.f, 0.f, 0.f};
    #pragma unroll
    for (int i = 0; i < 32; ++i) {
        #pragma unroll
        for (int rg = 0; rg < 4; ++rg) {
            float e = __expf(acc[i][rg]);   // logits in [-1,1]: exp safe
            acc[i][rg] = e;
            ps[rg] += e;
        }
    }
    #pragma unroll
    for (int off = 1; off < 16; off <<= 1) {
        #pragma unroll
        for (int rg = 0; rg < 4; ++rg) ps[rg] += __shfl_xor(ps[rg], off, 64);
    }
    if (l15 == 0) {
        #pragma unroll
        for (int rg = 0; rg < 4; ++rg) Ssum[wave][quad * 4 + rg] = ps[rg];
    }
    __syncthreads();                    // also: all ds_reads of Bs complete
    float inv[4];
    #pragma unroll
    for (int rg = 0; rg < 4; ++rg) {
        float s = 0.f;
        #pragma unroll
        for (int w = 0; w < 8; ++w) s += Ssum[w][quad * 4 + rg];
        inv[rg] = 1.0f / s;             // s >= 4096/e: no eps needed
    }

    // Two 2048-col chunks through obuf; NT float4 stores of full lines.
    #pragma unroll
    for (int c = 0; c < 2; ++c) {
        if (c) __syncthreads();         // chunk-0 read-back done
        #pragma unroll
        for (int ii = 0; ii < 16; ++ii) {
            #pragma unroll
            for (int rg = 0; rg < 4; ++rg)
                obuf[quad * 4 + rg][ii * 128 + wave * 16 + l15] =
                    acc[c * 16 + ii][rg] * inv[rg];
        }
        __syncthreads();
        float* obase = out + ((size_t)n * HW + t0) * HW + c * 2048;
        #pragma unroll
        for (int k = 0; k < 16; ++k) {
            f32x4 v = *(const f32x4*)&obuf[k][tid * 4];
            __builtin_nontemporal_store(
                v, (f32x4*)(obase + (size_t)k * HW + tid * 4));
        }
    }
}

extern "C" void kernel_launch(void* const* d_in, const int* in_sizes, int n_in,
                              void* d_out, int out_size, void* d_ws, size_t ws_size,
                              hipStream_t stream) {
    const float* ft = (const float*)d_in[0];   // [4096,128]
    const float* fr = (const float*)d_in[1];   // [8,128,4096]
    float* out = (float*)d_out;                // [8,4096,4096]

    char* ws = (char*)d_ws;
    bf16* ftn = (bf16*)ws;                     // 1 MB
    bf16* frt = (bf16*)(ws + (1 << 20));       // 8 MB

    norm_tar<<<HW, 64, 0, stream>>>(ft, ftn);
    norm_refs<<<(NCTX * HW) / 256, 256, 0, stream>>>(fr, frt);
    affinity_fused<<<NCTX * (HW / 16), 512, 0, stream>>>(ftn, frt, out);
}